// Round 3
// baseline (2044.113 us; speedup 1.0000x reference)
//
#include <hip/hip_runtime.h>

typedef unsigned int u32;
typedef unsigned short u16;
typedef unsigned long long u64;
typedef __attribute__((ext_vector_type(8))) short short8;   // 8 bf16 = 4 VGPRs (MFMA A/B frag)
typedef __attribute__((ext_vector_type(4))) float floatx4;  // MFMA C/D frag

#define BB 8
#define SS 256
#define VV 32000
#define EE 512
#define HH 1024
#define GRU_BLOCKS 16
#define GRU_THREADS 768
#define NCHUNK 500       // 32000 / 64

__device__ __forceinline__ float b2f(u16 h) {
  union { u32 u; float f; } c; c.u = ((u32)h) << 16; return c.f;
}
__device__ __forceinline__ u16 f2b_bits(u32 u) {
  return (u16)((u + 0x7FFFu + ((u >> 16) & 1u)) >> 16);  // RNE
}
__device__ __forceinline__ u16 f2b(float f) {
  union { float f; u32 u; } c; c.f = f; return f2b_bits(c.u);
}

// ---------------- dtype detector: 1 = inputs are bf16, 0 = fp32 ----------------
__global__ __launch_bounds__(256) void k_detect(const u32* __restrict__ w, int* __restrict__ dflag) {
  __shared__ int cnt;
  if (threadIdx.x == 0) cnt = 0;
  __syncthreads();
  int c = 0;
  for (int i = threadIdx.x; i < 8192; i += 256) {
    u32 e8 = (w[i] >> 7) & 0xFF;
    c += (e8 >= 100 && e8 <= 144);
  }
  atomicAdd(&cnt, c);
  __syncthreads();
  if (threadIdx.x == 0) dflag[0] = (cnt * 2 > 8192) ? 1 : 0;
}

// ---------------- edge normalization: any float input -> bf16 ws copy ----------------
__global__ __launch_bounds__(256) void k_conv(const void* __restrict__ src, u16* __restrict__ dst,
                                              int n, const int* __restrict__ dflag) {
  int i = (blockIdx.x * 256 + threadIdx.x) * 8;
  if (i >= n) return;
  if (dflag[0]) {
    *(uint4*)(dst + i) = *(const uint4*)((const u16*)src + i);
  } else {
    const float* s = (const float*)src + i;
    uint4 a = *(const uint4*)s, b = *(const uint4*)(s + 4);
    u32 w0 = ((u32)f2b_bits(a.y) << 16) | f2b_bits(a.x);
    u32 w1 = ((u32)f2b_bits(a.w) << 16) | f2b_bits(a.z);
    u32 w2 = ((u32)f2b_bits(b.y) << 16) | f2b_bits(b.x);
    u32 w3 = ((u32)f2b_bits(b.w) << 16) | f2b_bits(b.z);
    uint4 r; r.x = w0; r.y = w1; r.z = w2; r.w = w3;
    *(uint4*)(dst + i) = r;
  }
}

// ---------------- init: zero tagged h-exchange buffer (+ optional dflag force) ----------------
// h_tag word = (bf16 value << 16) | step_tag. Zero = h:0, tag:0 == what step 0 expects.
__global__ __launch_bounds__(256) void k_init(u32* h_tag, int* dflag, int setflag) {
  int t = threadIdx.x;
  for (int i = t; i < 2 * 8192; i += 256) h_tag[i] = 0;
  if (t == 0 && setflag >= 0) dflag[0] = setflag;
}

// ---------------- embedding gather ----------------
__global__ __launch_bounds__(64) void k_gather(const int* __restrict__ x,
                                               const u16* __restrict__ embW,
                                               u16* __restrict__ emb,
                                               u16* __restrict__ feat) {
  int row = blockIdx.x, l = threadIdx.x;
  int tok = x[row];
  uint4 v = ((const uint4*)(embW + (size_t)tok * EE))[l];
  ((uint4*)(emb + (size_t)row * EE))[l] = v;
  ((uint4*)(feat + (size_t)row * 1536 + HH))[l] = v;   // feat = [ctx | emb]
}

// ---------------- shared GEMM core: C[128x128] = A[128xK] * B[128xK]^T ----------------
template <int KTOT>
__device__ __forceinline__ void gemm_core(const u16* __restrict__ A, int lda,
                                          const u16* __restrict__ Bm, int ldb,
                                          int m0, int n0, floatx4 acc[4][4]) {
  __shared__ __align__(16) u16 As[128 * 64];
  __shared__ __align__(16) u16 Bs[128 * 64];
  const int tid = threadIdx.x;
  const int lane = tid & 63, w = tid >> 6;
  const int wm = w & 1, wn = w >> 1;
  const int col16 = lane & 15, quad = lane >> 4;
  floatx4 z = {0.f, 0.f, 0.f, 0.f};
  for (int i = 0; i < 4; i++)
    for (int j = 0; j < 4; j++) acc[i][j] = z;

  for (int k0 = 0; k0 < KTOT; k0 += 64) {
#pragma unroll
    for (int i = 0; i < 4; i++) {
      int c = tid + i * 256;
      int r = c >> 3, off = (c & 7) * 8;
      *(uint4*)&As[r * 64 + off] = *(const uint4*)&A[(size_t)(m0 + r) * lda + k0 + off];
      *(uint4*)&Bs[r * 64 + off] = *(const uint4*)&Bm[(size_t)(n0 + r) * ldb + k0 + off];
    }
    __syncthreads();
#pragma unroll
    for (int kk = 0; kk < 2; kk++) {
      short8 af[4], bf[4];
#pragma unroll
      for (int i = 0; i < 4; i++) {
        af[i] = *(const short8*)&As[(wm * 64 + i * 16 + col16) * 64 + kk * 32 + quad * 8];
        bf[i] = *(const short8*)&Bs[(wn * 64 + i * 16 + col16) * 64 + kk * 32 + quad * 8];
      }
#pragma unroll
      for (int i = 0; i < 4; i++)
#pragma unroll
        for (int j = 0; j < 4; j++)
          acc[i][j] = __builtin_amdgcn_mfma_f32_16x16x32_bf16(af[i], bf[j], acc[i][j], 0, 0, 0);
    }
    __syncthreads();
  }
}

// ---------------- gx = emb @ W_ih^T + b_ih, scattered to [s][gb][48][8] fp32 ----------------
__global__ __launch_bounds__(256) void k_gx(const u16* __restrict__ emb,
                                            const u16* __restrict__ W_ih,
                                            const u16* __restrict__ b_ih,
                                            float* __restrict__ gx2) {
  floatx4 acc[4][4];
  int bm = blockIdx.x, bn = blockIdx.y;
  gemm_core<EE>(emb, EE, W_ih, EE, bm * 128, bn * 128, acc);
  const int tid = threadIdx.x, lane = tid & 63, w = tid >> 6;
  const int wm = w & 1, wn = w >> 1, col16 = lane & 15, quad = lane >> 4;
#pragma unroll
  for (int j = 0; j < 4; j++) {
    int g = bn * 128 + wn * 64 + j * 16 + col16;
    float bias = b2f(b_ih[g]);
    int grp = g >> 10, colh = g & 1023;
    int gb = colh >> 4, slot = grp * 16 + (colh & 15);
#pragma unroll
    for (int i = 0; i < 4; i++)
#pragma unroll
      for (int e = 0; e < 4; e++) {
        int row = bm * 128 + wm * 64 + i * 16 + quad * 4 + e;
        int b = row >> 8, s = row & 255;
        gx2[((size_t)(s * 64 + gb) * 48 + slot) * 8 + b] = acc[i][j][e] + bias;
      }
  }
}

// ---------------- persistent GRU scan, fence-free tagged exchange ----------------
// 16 blocks x 768 threads (12 MFMA waves). Block blk owns h cols [blk*64, blk*64+64).
// h exchange: h_tag[slot][b*1024+col] u32 = (bf16 h << 16) | step_tag, slot = step&1.
// Readers poll the data words themselves (relaxed agent atomics) -> single-hop, no flags.
// Own-block columns are NOT polled: combine writes them straight into h_lds.
// __launch_bounds__(768, 3): 3 waves/SIMD = 1 block/CU (all we ever have: 16 blocks on
// 256 CUs) -> VGPR cap ~168, so the 128-VGPR Wf W_hh cache stays in registers. Without
// the min-waves hint the compiler targeted 2 blocks/CU (cap 84) and spilled all of Wf
// to scratch (round-2 regression: VGPR_Count=84, ~6.3 MB/step scratch reloads).
__global__ __launch_bounds__(GRU_THREADS, 3) void k_gru(const u16* __restrict__ W_hh,
                                                        const u16* __restrict__ b_hh,
                                                        const int* __restrict__ x,
                                                        const float* __restrict__ gx2,
                                                        u32* __restrict__ h_tag,
                                                        u16* __restrict__ feat) {
  __shared__ __align__(16) u16 h_lds[16][1032];  // rows 8..15 stay zero (MFMA M-pad)
  __shared__ float gh[3][64][8];
  __shared__ float hold[64][8];
  __shared__ float bhh[192];
  __shared__ int x_s[2048];

  const int tid = threadIdx.x;
  const int lane = tid & 63, w = tid >> 6;       // 12 waves: gate g=w>>2, col-quarter cq=w&3
  const int blk = blockIdx.x, hc = blk * 64;
  const int col16 = lane & 15, quad = lane >> 4;

  for (int i = tid; i < 16 * 1032; i += GRU_THREADS) ((u16*)h_lds)[i] = 0;
  for (int i = tid; i < 2048; i += GRU_THREADS) x_s[i] = x[i];
  if (tid < 512) hold[tid & 63][tid >> 6] = 0.f;
  if (tid < 192) bhh[tid] = b2f(b_hh[(tid >> 6) * HH + hc + (tid & 63)]);

  short8 Wf[32];
  {
    int g = w >> 2, cq = w & 3;
    int grow = g * HH + hc + cq * 16 + col16;
    const u16* wp = W_hh + (size_t)grow * HH + quad * 8;
#pragma unroll
    for (int t = 0; t < 32; t++) Wf[t] = *(const short8*)(wp + t * 32);
  }
  __syncthreads();

  const int cj = tid & 63, cb = tid >> 6;        // combine mapping (tid < 512)
#pragma unroll 1
  for (int s = 0; s < SS; s++) {
    // prefetch this step's input gates (independent of h)
    float xr = 0.f, xz = 0.f, xn = 0.f;
    if (tid < 512) {
      int col = hc + cj;
      const float* gp = gx2 + (size_t)(s * 64 + (col >> 4)) * 384;
      int c16 = col & 15;
      xr = gp[c16 * 8 + cb];
      xz = gp[128 + c16 * 8 + cb];
      xn = gp[256 + c16 * 8 + cb];
    }
    // stage remote h: poll tagged words, extract bf16 into LDS. Own cols skipped.
    {
      const u64* hb = (const u64*)(h_tag + (size_t)(s & 1) * 8192);
      const u32 want = (u32)(s & 0xFFFF);
      u64 vals[6];
      u32 pend = 0;
#pragma unroll
      for (int i = 0; i < 6; i++) {
        int pr = tid + i * GRU_THREADS;
        if (pr < 4096 && ((pr & 511) >> 5) != blk) pend |= 1u << i;  // skip own 64 cols
      }
      int guard = 0;
      while (pend) {
#pragma unroll
        for (int i = 0; i < 6; i++)
          if (pend & (1u << i))
            vals[i] = __hip_atomic_load(hb + (tid + i * GRU_THREADS),
                                        __ATOMIC_RELAXED, __HIP_MEMORY_SCOPE_AGENT);
#pragma unroll
        for (int i = 0; i < 6; i++)
          if (pend & (1u << i)) {
            u64 v = vals[i];
            if ((u32)(v & 0xFFFFu) == want && ((u32)(v >> 32) & 0xFFFFu) == want) {
              int pr = tid + i * GRU_THREADS;
              u32 packed = ((u32)(v >> 16) & 0xFFFFu) | ((u32)(v >> 48) << 16);
              *(u32*)&h_lds[pr >> 9][(pr & 511) * 2] = packed;
              pend &= ~(1u << i);
            }
          }
        if (pend) {
          if (++guard > (1 << 15)) break;  // livelock safety (wrong results, no hang)
        }
      }
    }
    __syncthreads();
    // g_h = h @ W_hh^T for this wave's 16 gate rows (K=1024: 32 MFMAs, 2 chains)
    {
      const u16* hp = &h_lds[col16][quad * 8];
      floatx4 a0 = {0.f, 0.f, 0.f, 0.f}, a1 = {0.f, 0.f, 0.f, 0.f};
#pragma unroll
      for (int t = 0; t < 32; t += 2) {
        short8 f0 = *(const short8*)(hp + t * 32);
        short8 f1 = *(const short8*)(hp + t * 32 + 32);
        a0 = __builtin_amdgcn_mfma_f32_16x16x32_bf16(f0, Wf[t], a0, 0, 0, 0);
        a1 = __builtin_amdgcn_mfma_f32_16x16x32_bf16(f1, Wf[t + 1], a1, 0, 0, 0);
      }
      a0 += a1;
      if (quad < 2) {
        int g = w >> 2, cq = w & 3;
#pragma unroll
        for (int e = 0; e < 4; e++) gh[g][cq * 16 + col16][quad * 4 + e] = a0[e];
      }
    }
    __syncthreads();
    // gate combine + state update + tagged publish for owned 64 h-cols x 8 batches
    if (tid < 512) {
      float hr = gh[0][cj][cb] + bhh[cj];
      float hz = gh[1][cj][cb] + bhh[64 + cj];
      float hn = gh[2][cj][cb] + bhh[128 + cj];
      float r = 1.f / (1.f + __expf(-(xr + hr)));
      float z = 1.f / (1.f + __expf(-(xz + hz)));
      float tn = xn + r * hn;
      float n = 1.f - 2.f / (1.f + __expf(2.f * tn));  // tanh via exp
      float ho = hold[cj][cb];
      float hnew = (1.f - z) * n + z * ho;
      int pad = (x_s[cb * SS + s] == 0);
      if (pad) hnew = ho;
      hold[cj][cb] = hnew;
      u16 hb16 = f2b(hnew);
      u32 tw = ((u32)hb16 << 16) | (u32)((s + 1) & 0xFFFF);
      __hip_atomic_store(h_tag + (size_t)((s + 1) & 1) * 8192 + cb * 1024 + hc + cj, tw,
                         __ATOMIC_RELAXED, __HIP_MEMORY_SCOPE_AGENT);
      h_lds[cb][hc + cj] = hb16;   // own cols bypass global round-trip (next step reads LDS)
      feat[(size_t)(cb * SS + s) * 1536 + hc + cj] = pad ? (u16)0 : hb16;
    }
    // no sync needed here: next staging writes disjoint h_lds regions (own cols excluded
    // from poll), and all MFMA reads completed at the gh-sync barrier.
  }
}

// ---------------- logits = tanh(feat @ lin_W^T + lin_b) ----------------
__global__ __launch_bounds__(256) void k_lin(const u16* __restrict__ feat,
                                             const u16* __restrict__ lin_W,
                                             const u16* __restrict__ lin_b,
                                             u16* __restrict__ logits) {
  floatx4 acc[4][4];
  int bm = blockIdx.x, bn = blockIdx.y;
  gemm_core<1536>(feat, 1536, lin_W, 1536, bm * 128, bn * 128, acc);
  const int tid = threadIdx.x, lane = tid & 63, w = tid >> 6;
  const int wm = w & 1, wn = w >> 1, col16 = lane & 15, quad = lane >> 4;
#pragma unroll
  for (int j = 0; j < 4; j++) {
    int col = bn * 128 + wn * 64 + j * 16 + col16;
    float bias = b2f(lin_b[col]);
#pragma unroll
    for (int i = 0; i < 4; i++)
#pragma unroll
      for (int e = 0; e < 4; e++) {
        int row = bm * 128 + wm * 64 + i * 16 + quad * 4 + e;
        logits[(size_t)row * EE + col] = f2b(tanhf(acc[i][j][e] + bias));
      }
  }
}

// ---------------- scores = logits @ emb_W^T (dual-dtype out) + per-chunk sumexp ----------------
__global__ __launch_bounds__(256) void k_scores(const u16* __restrict__ logits,
                                                const u16* __restrict__ embW,
                                                void* __restrict__ outv,
                                                float* __restrict__ partial,
                                                const int* __restrict__ dflag) {
  floatx4 acc[4][4];
  int bm = blockIdx.x, bn = blockIdx.y;
  gemm_core<EE>(logits, EE, embW, EE, bm * 128, bn * 128, acc);
  const int tid = threadIdx.x, lane = tid & 63, w = tid >> 6;
  const int wm = w & 1, wn = w >> 1, col16 = lane & 15, quad = lane >> 4;
  const int bf = dflag[0];
  u16* out16 = (u16*)outv;
  float* out32 = (float*)outv;
#pragma unroll
  for (int i = 0; i < 4; i++) {
#pragma unroll
    for (int e = 0; e < 4; e++) {
      int row = bm * 128 + wm * 64 + i * 16 + quad * 4 + e;
      size_t ob = (size_t)row * VV + bn * 128 + wn * 64;
      float sl = 0.f;
#pragma unroll
      for (int j = 0; j < 4; j++) {
        float v = acc[i][j][e];
        if (bf) out16[ob + j * 16 + col16] = f2b(v);
        else    out32[ob + j * 16 + col16] = v;
        sl += __expf(v);  // |score| <= ~30 by Cauchy-Schwarz: fp32-safe without max
      }
      sl += __shfl_xor(sl, 1, 64);
      sl += __shfl_xor(sl, 2, 64);
      sl += __shfl_xor(sl, 4, 64);
      sl += __shfl_xor(sl, 8, 64);
      if (col16 == 0) partial[(size_t)row * NCHUNK + bn * 2 + wn] = sl;
    }
  }
}

// ---------------- lse[row] = log(sum of 500 chunk sums) ----------------
__global__ __launch_bounds__(64) void k_lse(const float* __restrict__ partial,
                                            float* __restrict__ lse) {
  int row = blockIdx.x, lane = threadIdx.x;
  float s = 0.f;
  for (int c = lane; c < NCHUNK; c += 64) s += partial[(size_t)row * NCHUNK + c];
#pragma unroll
  for (int d = 32; d >= 1; d >>= 1) s += __shfl_xor(s, d, 64);
  if (lane == 0) lse[row] = logf(s);
}

// ---------------- out -= lse[row] (in place, 16 B per thread, dual dtype) ----------------
__global__ __launch_bounds__(256) void k_fix(void* __restrict__ outv,
                                             const float* __restrict__ lse,
                                             const int* __restrict__ dflag) {
  int g = blockIdx.x * 256 + threadIdx.x;      // grid: 64000*256 = 16,384,000 granules
  if (dflag[0]) {
    if (g >= 8192000) return;                  // 8,192,000 uint4 of bf16 out; 4000/row
    u16* out = (u16*)outv;
    int row = g / 4000;
    float l = lse[row];
    uint4 v = ((const uint4*)out)[g];
    u32 a[4] = {v.x, v.y, v.z, v.w};
#pragma unroll
    for (int k = 0; k < 4; k++) {
      float lo = b2f((u16)(a[k] & 0xffff)) - l;
      float hi = b2f((u16)(a[k] >> 16)) - l;
      a[k] = ((u32)f2b(hi) << 16) | (u32)f2b(lo);
    }
    uint4 r; r.x = a[0]; r.y = a[1]; r.z = a[2]; r.w = a[3];
    ((uint4*)out)[g] = r;
  } else {
    float* out = (float*)outv;                 // 16,384,000 float4; 8000/row
    int row = g / 8000;
    float l = lse[row];
    float4 v = ((const float4*)out)[g];
    v.x -= l; v.y -= l; v.z -= l; v.w -= l;
    ((float4*)out)[g] = v;
  }
}

extern "C" void kernel_launch(void* const* d_in, const int* in_sizes, int n_in,
                              void* d_out, int out_size, void* d_ws, size_t ws_size,
                              hipStream_t stream) {
  const int* x = (const int*)d_in[0];

  char* ws = (char*)d_ws;
  float* gx2     = (float*)(ws);              // 25,165,824 B  [s][64][48][8] fp32
  u16*   feat    = (u16*)(ws + 25165824);     //  6,291,456 B  [2048][1536] bf16
  u16*   emb     = (u16*)(ws + 31457280);     //  2,097,152 B  [2048][512]  bf16
  u16*   logits  = (u16*)(ws + 33554432);     //  2,097,152 B  [2048][512]  bf16
  u32*   h_tag   = (u32*)(ws + 35651584);     //     65,536 B  [2][8][1024] tagged u32
  float* partial = (float*)(ws + 35717120);   //  4,096,000 B  [2048][500] fp32
  float* lse     = (float*)(ws + 39813120);   //      8,192 B  [2048] fp32
  int*   dflag   = (int*)(ws + 39821312);     //        256 B
  u16*   embW_c  = (u16*)(ws + 39821568);     // 32,768,000 B
  u16*   Wih_c   = (u16*)(ws + 72589568);     //  3,145,728 B
  u16*   Whh_c   = (u16*)(ws + 75735296);     //  6,291,456 B
  u16*   linW_c  = (u16*)(ws + 82026752);     //  1,572,864 B
  u16*   bih_c   = (u16*)(ws + 83599616);     //      6,144 B
  u16*   bhh_c   = (u16*)(ws + 83605760);     //      6,144 B
  u16*   linb_c  = (u16*)(ws + 83611904);     //      1,024 B
  const size_t TOTAL_WS = 83612928;

  const u16 *embW, *W_ih, *W_hh, *b_ih, *b_hh, *lin_W, *lin_b;
  if (ws_size >= TOTAL_WS) {
    k_detect<<<1, 256, 0, stream>>>((const u32*)d_in[1], dflag);
    k_init<<<1, 256, 0, stream>>>(h_tag, dflag, -1);
    k_conv<<<8000, 256, 0, stream>>>(d_in[1], embW_c, VV * EE, dflag);
    k_conv<<<1536, 256, 0, stream>>>(d_in[3], Whh_c, 3 * HH * HH, dflag);
    k_conv<<<768,  256, 0, stream>>>(d_in[2], Wih_c, 3 * HH * EE, dflag);
    k_conv<<<384,  256, 0, stream>>>(d_in[6], linW_c, EE * (HH + EE), dflag);
    k_conv<<<2,    256, 0, stream>>>(d_in[4], bih_c, 3 * HH, dflag);
    k_conv<<<2,    256, 0, stream>>>(d_in[5], bhh_c, 3 * HH, dflag);
    k_conv<<<1,    256, 0, stream>>>(d_in[7], linb_c, EE, dflag);
    embW = embW_c; W_ih = Wih_c; W_hh = Whh_c; b_ih = bih_c;
    b_hh = bhh_c; lin_W = linW_c; lin_b = linb_c;
  } else {
    k_init<<<1, 256, 0, stream>>>(h_tag, dflag, 1);
    embW = (const u16*)d_in[1]; W_ih = (const u16*)d_in[2]; W_hh = (const u16*)d_in[3];
    b_ih = (const u16*)d_in[4]; b_hh = (const u16*)d_in[5];
    lin_W = (const u16*)d_in[6]; lin_b = (const u16*)d_in[7];
  }

  k_gather<<<2048, 64, 0, stream>>>(x, embW, emb, feat);
  k_gx<<<dim3(16, 24), 256, 0, stream>>>(emb, W_ih, b_ih, gx2);
  k_gru<<<GRU_BLOCKS, GRU_THREADS, 0, stream>>>(W_hh, b_hh, x, gx2, h_tag, feat);
  k_lin<<<dim3(16, 4), 256, 0, stream>>>(feat, lin_W, lin_b, logits);
  k_scores<<<dim3(16, 250), 256, 0, stream>>>(logits, embW, d_out, partial, dflag);
  k_lse<<<2048, 64, 0, stream>>>(partial, lse);
  k_fix<<<64000, 256, 0, stream>>>(d_out, lse, dflag);
}

// Round 4
// 1807.243 us; speedup vs baseline: 1.1311x; 1.1311x over previous
//
#include <hip/hip_runtime.h>

typedef unsigned int u32;
typedef unsigned short u16;
typedef unsigned long long u64;
typedef __attribute__((ext_vector_type(8))) short short8;   // 8 bf16 = 4 VGPRs (MFMA A/B frag)
typedef __attribute__((ext_vector_type(4))) float floatx4;  // MFMA C/D frag

#define BB 8
#define SS 256
#define VV 32000
#define EE 512
#define HH 1024
#define GRU_BLOCKS 64
#define GRU_THREADS 192
#define NCHUNK 500       // 32000 / 64

__device__ __forceinline__ float b2f(u16 h) {
  union { u32 u; float f; } c; c.u = ((u32)h) << 16; return c.f;
}
__device__ __forceinline__ u16 f2b_bits(u32 u) {
  return (u16)((u + 0x7FFFu + ((u >> 16) & 1u)) >> 16);  // RNE
}
__device__ __forceinline__ u16 f2b(float f) {
  union { float f; u32 u; } c; c.f = f; return f2b_bits(c.u);
}

// ---------------- dtype detector: 1 = inputs are bf16, 0 = fp32 ----------------
__global__ __launch_bounds__(256) void k_detect(const u32* __restrict__ w, int* __restrict__ dflag) {
  __shared__ int cnt;
  if (threadIdx.x == 0) cnt = 0;
  __syncthreads();
  int c = 0;
  for (int i = threadIdx.x; i < 8192; i += 256) {
    u32 e8 = (w[i] >> 7) & 0xFF;
    c += (e8 >= 100 && e8 <= 144);
  }
  atomicAdd(&cnt, c);
  __syncthreads();
  if (threadIdx.x == 0) dflag[0] = (cnt * 2 > 8192) ? 1 : 0;
}

// ---------------- edge normalization: any float input -> bf16 ws copy ----------------
__global__ __launch_bounds__(256) void k_conv(const void* __restrict__ src, u16* __restrict__ dst,
                                              int n, const int* __restrict__ dflag) {
  int i = (blockIdx.x * 256 + threadIdx.x) * 8;
  if (i >= n) return;
  if (dflag[0]) {
    *(uint4*)(dst + i) = *(const uint4*)((const u16*)src + i);
  } else {
    const float* s = (const float*)src + i;
    uint4 a = *(const uint4*)s, b = *(const uint4*)(s + 4);
    u32 w0 = ((u32)f2b_bits(a.y) << 16) | f2b_bits(a.x);
    u32 w1 = ((u32)f2b_bits(a.w) << 16) | f2b_bits(a.z);
    u32 w2 = ((u32)f2b_bits(b.y) << 16) | f2b_bits(b.x);
    u32 w3 = ((u32)f2b_bits(b.w) << 16) | f2b_bits(b.z);
    uint4 r; r.x = w0; r.y = w1; r.z = w2; r.w = w3;
    *(uint4*)(dst + i) = r;
  }
}

// ---------------- init: zero tagged h-exchange buffer + flags (+ optional dflag force) ----
// h_tag word = (bf16 value << 16) | step_tag. Zero = h:0, tag:0 == what step 0 expects.
// flags[slot][blk] advisory "block blk published step s" hints; zero == step 0 ready.
__global__ __launch_bounds__(256) void k_init(u32* h_tag, u32* flags, int* dflag, int setflag) {
  int t = threadIdx.x;
  for (int i = t; i < 2 * 8192; i += 256) h_tag[i] = 0;
  if (t < 128) flags[t] = 0;
  if (t == 0 && setflag >= 0) dflag[0] = setflag;
}

// ---------------- embedding gather ----------------
__global__ __launch_bounds__(64) void k_gather(const int* __restrict__ x,
                                               const u16* __restrict__ embW,
                                               u16* __restrict__ emb,
                                               u16* __restrict__ feat) {
  int row = blockIdx.x, l = threadIdx.x;
  int tok = x[row];
  uint4 v = ((const uint4*)(embW + (size_t)tok * EE))[l];
  ((uint4*)(emb + (size_t)row * EE))[l] = v;
  ((uint4*)(feat + (size_t)row * 1536 + HH))[l] = v;   // feat = [ctx | emb]
}

// ---------------- shared GEMM core: C[128x128] = A[128xK] * B[128xK]^T ----------------
template <int KTOT>
__device__ __forceinline__ void gemm_core(const u16* __restrict__ A, int lda,
                                          const u16* __restrict__ Bm, int ldb,
                                          int m0, int n0, floatx4 acc[4][4]) {
  __shared__ __align__(16) u16 As[128 * 64];
  __shared__ __align__(16) u16 Bs[128 * 64];
  const int tid = threadIdx.x;
  const int lane = tid & 63, w = tid >> 6;
  const int wm = w & 1, wn = w >> 1;
  const int col16 = lane & 15, quad = lane >> 4;
  floatx4 z = {0.f, 0.f, 0.f, 0.f};
  for (int i = 0; i < 4; i++)
    for (int j = 0; j < 4; j++) acc[i][j] = z;

  for (int k0 = 0; k0 < KTOT; k0 += 64) {
#pragma unroll
    for (int i = 0; i < 4; i++) {
      int c = tid + i * 256;
      int r = c >> 3, off = (c & 7) * 8;
      *(uint4*)&As[r * 64 + off] = *(const uint4*)&A[(size_t)(m0 + r) * lda + k0 + off];
      *(uint4*)&Bs[r * 64 + off] = *(const uint4*)&Bm[(size_t)(n0 + r) * ldb + k0 + off];
    }
    __syncthreads();
#pragma unroll
    for (int kk = 0; kk < 2; kk++) {
      short8 af[4], bf[4];
#pragma unroll
      for (int i = 0; i < 4; i++) {
        af[i] = *(const short8*)&As[(wm * 64 + i * 16 + col16) * 64 + kk * 32 + quad * 8];
        bf[i] = *(const short8*)&Bs[(wn * 64 + i * 16 + col16) * 64 + kk * 32 + quad * 8];
      }
#pragma unroll
      for (int i = 0; i < 4; i++)
#pragma unroll
        for (int j = 0; j < 4; j++)
          acc[i][j] = __builtin_amdgcn_mfma_f32_16x16x32_bf16(af[i], bf[j], acc[i][j], 0, 0, 0);
    }
    __syncthreads();
  }
}

// ---------------- gx = emb @ W_ih^T + b_ih, scattered to [s][gb][48][8] fp32 ----------------
__global__ __launch_bounds__(256) void k_gx(const u16* __restrict__ emb,
                                            const u16* __restrict__ W_ih,
                                            const u16* __restrict__ b_ih,
                                            float* __restrict__ gx2) {
  floatx4 acc[4][4];
  int bm = blockIdx.x, bn = blockIdx.y;
  gemm_core<EE>(emb, EE, W_ih, EE, bm * 128, bn * 128, acc);
  const int tid = threadIdx.x, lane = tid & 63, w = tid >> 6;
  const int wm = w & 1, wn = w >> 1, col16 = lane & 15, quad = lane >> 4;
#pragma unroll
  for (int j = 0; j < 4; j++) {
    int g = bn * 128 + wn * 64 + j * 16 + col16;
    float bias = b2f(b_ih[g]);
    int grp = g >> 10, colh = g & 1023;
    int gb = colh >> 4, slot = grp * 16 + (colh & 15);
#pragma unroll
    for (int i = 0; i < 4; i++)
#pragma unroll
      for (int e = 0; e < 4; e++) {
        int row = bm * 128 + wm * 64 + i * 16 + quad * 4 + e;
        int b = row >> 8, s = row & 255;
        gx2[((size_t)(s * 64 + gb) * 48 + slot) * 8 + b] = acc[i][j][e] + bias;
      }
  }
}

// ---------------- persistent GRU scan, advisory-flag + authoritative-tag exchange ----------
// 64 blocks x 192 threads (round-0 geometry, best measured). Block blk owns h cols
// [blk*16, blk*16+16). h exchange: h_tag[slot][b*1024+col] u32 = (bf16 h << 16) | step_tag.
// Producer fires 128 tagged data stores + 1 flag store back-to-back, NO waits (the round-1
// mistake was draining vmcnt before the flag: +2 serialized hops, +2.2us/step). Flag is
// only a TIMING HINT; consumers: 64 threads spin on one flag word each (round = 1 load
// ~= 1 RT, avg detect ~0.5 RT after visible) -> barrier -> ONE bulk tagged load of all
// 22 words (1 RT) -> tag verify catches any data word that lagged its flag (retry loop =
// graceful fallback to plain polling). Own-block cols skip the global round-trip entirely:
// combine writes them straight into h_lds.
__global__ __launch_bounds__(GRU_THREADS) void k_gru(const u16* __restrict__ W_hh,
                                                     const u16* __restrict__ b_hh,
                                                     const int* __restrict__ x,
                                                     const float* __restrict__ gx2,
                                                     u32* __restrict__ h_tag,
                                                     u32* __restrict__ flags,
                                                     u16* __restrict__ feat) {
  __shared__ __align__(16) u16 h_lds[16][1032];  // rows 8..15 stay zero (MFMA M-pad)
  __shared__ float gh[3][16][8];
  __shared__ float hold[16][8];
  __shared__ float bhh[48];
  __shared__ int x_s[2048];

  const int tid = threadIdx.x;
  const int lane = tid & 63, w = tid >> 6;       // 3 waves: r, z, n
  const int blk = blockIdx.x, hc = blk * 16;
  const int col16 = lane & 15, quad = lane >> 4;

  for (int i = tid; i < 16 * 1032; i += GRU_THREADS) ((u16*)h_lds)[i] = 0;
  for (int i = tid; i < 2048; i += GRU_THREADS) x_s[i] = x[i];
  if (tid < 128) hold[tid & 15][tid >> 4] = 0.f;
  if (tid < 48) bhh[tid] = b2f(b_hh[(tid >> 4) * HH + hc + (tid & 15)]);

  short8 Wf[32];
  {
    int grow = w * HH + hc + col16;
    const u16* wp = W_hh + (size_t)grow * HH + quad * 8;
#pragma unroll
    for (int t = 0; t < 32; t++) Wf[t] = *(const short8*)(wp + t * 32);
  }
  __syncthreads();

  const int cj = tid & 15, cb = tid >> 4;
#pragma unroll 1
  for (int s = 0; s < SS; s++) {
    // prefetch this step's input gates (independent of h; latency hides under flag wait)
    float xr = 0.f, xz = 0.f, xn = 0.f;
    if (tid < 128) {
      const float* gp = gx2 + (size_t)(s * 64 + blk) * 384;
      xr = gp[cj * 8 + cb];
      xz = gp[128 + cj * 8 + cb];
      xn = gp[256 + cj * 8 + cb];
    }
    // advisory flag gate: thread t<64 spins on block t's flag (own block skipped)
    if (tid < 64 && tid != blk) {
      const u32* fp = flags + (s & 1) * 64 + tid;
      int guard = 0;
      while (__hip_atomic_load(fp, __ATOMIC_RELAXED, __HIP_MEMORY_SCOPE_AGENT) != (u32)s) {
        if (++guard > (1 << 20)) break;  // livelock safety
      }
    }
    __syncthreads();
    // bulk tagged load + verify (typically one round). Own 16 cols skipped (LDS bypass).
    {
      const u64* hb = (const u64*)(h_tag + (size_t)(s & 1) * 8192);
      const u32 want = (u32)(s & 0xFFFF);
      u64 vals[22];
      u32 pend = 0;
#pragma unroll
      for (int i = 0; i < 22; i++) {
        int pr = tid + i * GRU_THREADS;
        if (pr < 4096 && ((pr & 511) >> 3) != blk) pend |= 1u << i;
      }
      int guard = 0;
      while (pend) {
#pragma unroll
        for (int i = 0; i < 22; i++)
          if (pend & (1u << i))
            vals[i] = __hip_atomic_load(hb + (tid + i * GRU_THREADS),
                                        __ATOMIC_RELAXED, __HIP_MEMORY_SCOPE_AGENT);
#pragma unroll
        for (int i = 0; i < 22; i++)
          if (pend & (1u << i)) {
            u64 v = vals[i];
            if ((u32)(v & 0xFFFFu) == want && ((u32)(v >> 32) & 0xFFFFu) == want) {
              int pr = tid + i * GRU_THREADS;
              u32 packed = ((u32)(v >> 16) & 0xFFFFu) | ((u32)(v >> 48) << 16);
              *(u32*)&h_lds[pr >> 9][(pr & 511) * 2] = packed;
              pend &= ~(1u << i);
            }
          }
        if (pend) {
          if (++guard > (1 << 14)) break;  // livelock safety (wrong results, no hang)
        }
      }
    }
    __syncthreads();
    // g_h = h @ W_hh^T for this wave's 16 gate rows (K=1024: 32 MFMAs, 2 chains)
    {
      const u16* hp = &h_lds[col16][quad * 8];
      floatx4 a0 = {0.f, 0.f, 0.f, 0.f}, a1 = {0.f, 0.f, 0.f, 0.f};
#pragma unroll
      for (int t = 0; t < 32; t += 2) {
        short8 f0 = *(const short8*)(hp + t * 32);
        short8 f1 = *(const short8*)(hp + t * 32 + 32);
        a0 = __builtin_amdgcn_mfma_f32_16x16x32_bf16(f0, Wf[t], a0, 0, 0, 0);
        a1 = __builtin_amdgcn_mfma_f32_16x16x32_bf16(f1, Wf[t + 1], a1, 0, 0, 0);
      }
      a0 += a1;
      if (quad < 2) {
#pragma unroll
        for (int e = 0; e < 4; e++) gh[w][col16][quad * 4 + e] = a0[e];
      }
    }
    __syncthreads();
    // gate combine + state update + tagged publish for owned 16 h-cols x 8 batches
    if (tid < 128) {
      float hr = gh[0][cj][cb] + bhh[cj];
      float hz = gh[1][cj][cb] + bhh[16 + cj];
      float hn = gh[2][cj][cb] + bhh[32 + cj];
      float r = 1.f / (1.f + __expf(-(xr + hr)));
      float z = 1.f / (1.f + __expf(-(xz + hz)));
      float tn = xn + r * hn;
      float n = 1.f - 2.f / (1.f + __expf(2.f * tn));  // tanh via exp
      float ho = hold[cj][cb];
      float hnew = (1.f - z) * n + z * ho;
      int pad = (x_s[cb * SS + s] == 0);
      if (pad) hnew = ho;
      hold[cj][cb] = hnew;
      u16 hb16 = f2b(hnew);
      u32 tw = ((u32)hb16 << 16) | (u32)((s + 1) & 0xFFFF);
      __hip_atomic_store(h_tag + (size_t)((s + 1) & 1) * 8192 + cb * 1024 + hc + cj, tw,
                         __ATOMIC_RELAXED, __HIP_MEMORY_SCOPE_AGENT);
      h_lds[cb][hc + cj] = hb16;   // own cols bypass global round-trip (next step reads LDS)
      feat[(size_t)(cb * SS + s) * 1536 + hc + cj] = pad ? (u16)0 : hb16;
    }
    // advisory flag: fire-and-forget, no drain (tags remain the authority)
    if (tid == 0)
      __hip_atomic_store(flags + ((s + 1) & 1) * 64 + blk, (u32)(s + 1),
                         __ATOMIC_RELAXED, __HIP_MEMORY_SCOPE_AGENT);
    // no sync needed here: next staging writes disjoint h_lds regions (own cols excluded
    // from the poll set), and all MFMA reads completed at the gh-sync barrier.
  }
}

// ---------------- logits = tanh(feat @ lin_W^T + lin_b) ----------------
__global__ __launch_bounds__(256) void k_lin(const u16* __restrict__ feat,
                                             const u16* __restrict__ lin_W,
                                             const u16* __restrict__ lin_b,
                                             u16* __restrict__ logits) {
  floatx4 acc[4][4];
  int bm = blockIdx.x, bn = blockIdx.y;
  gemm_core<1536>(feat, 1536, lin_W, 1536, bm * 128, bn * 128, acc);
  const int tid = threadIdx.x, lane = tid & 63, w = tid >> 6;
  const int wm = w & 1, wn = w >> 1, col16 = lane & 15, quad = lane >> 4;
#pragma unroll
  for (int j = 0; j < 4; j++) {
    int col = bn * 128 + wn * 64 + j * 16 + col16;
    float bias = b2f(lin_b[col]);
#pragma unroll
    for (int i = 0; i < 4; i++)
#pragma unroll
      for (int e = 0; e < 4; e++) {
        int row = bm * 128 + wm * 64 + i * 16 + quad * 4 + e;
        logits[(size_t)row * EE + col] = f2b(tanhf(acc[i][j][e] + bias));
      }
  }
}

// ---------------- scores = logits @ emb_W^T (dual-dtype out) + per-chunk sumexp ----------------
__global__ __launch_bounds__(256) void k_scores(const u16* __restrict__ logits,
                                                const u16* __restrict__ embW,
                                                void* __restrict__ outv,
                                                float* __restrict__ partial,
                                                const int* __restrict__ dflag) {
  floatx4 acc[4][4];
  int bm = blockIdx.x, bn = blockIdx.y;
  gemm_core<EE>(logits, EE, embW, EE, bm * 128, bn * 128, acc);
  const int tid = threadIdx.x, lane = tid & 63, w = tid >> 6;
  const int wm = w & 1, wn = w >> 1, col16 = lane & 15, quad = lane >> 4;
  const int bf = dflag[0];
  u16* out16 = (u16*)outv;
  float* out32 = (float*)outv;
#pragma unroll
  for (int i = 0; i < 4; i++) {
#pragma unroll
    for (int e = 0; e < 4; e++) {
      int row = bm * 128 + wm * 64 + i * 16 + quad * 4 + e;
      size_t ob = (size_t)row * VV + bn * 128 + wn * 64;
      float sl = 0.f;
#pragma unroll
      for (int j = 0; j < 4; j++) {
        float v = acc[i][j][e];
        if (bf) out16[ob + j * 16 + col16] = f2b(v);
        else    out32[ob + j * 16 + col16] = v;
        sl += __expf(v);  // |score| <= ~30 by Cauchy-Schwarz: fp32-safe without max
      }
      sl += __shfl_xor(sl, 1, 64);
      sl += __shfl_xor(sl, 2, 64);
      sl += __shfl_xor(sl, 4, 64);
      sl += __shfl_xor(sl, 8, 64);
      if (col16 == 0) partial[(size_t)row * NCHUNK + bn * 2 + wn] = sl;
    }
  }
}

// ---------------- lse[row] = log(sum of 500 chunk sums) ----------------
__global__ __launch_bounds__(64) void k_lse(const float* __restrict__ partial,
                                            float* __restrict__ lse) {
  int row = blockIdx.x, lane = threadIdx.x;
  float s = 0.f;
  for (int c = lane; c < NCHUNK; c += 64) s += partial[(size_t)row * NCHUNK + c];
#pragma unroll
  for (int d = 32; d >= 1; d >>= 1) s += __shfl_xor(s, d, 64);
  if (lane == 0) lse[row] = logf(s);
}

// ---------------- out -= lse[row] (in place, 16 B per thread, dual dtype) ----------------
__global__ __launch_bounds__(256) void k_fix(void* __restrict__ outv,
                                             const float* __restrict__ lse,
                                             const int* __restrict__ dflag) {
  int g = blockIdx.x * 256 + threadIdx.x;      // grid: 64000*256 = 16,384,000 granules
  if (dflag[0]) {
    if (g >= 8192000) return;                  // 8,192,000 uint4 of bf16 out; 4000/row
    u16* out = (u16*)outv;
    int row = g / 4000;
    float l = lse[row];
    uint4 v = ((const uint4*)out)[g];
    u32 a[4] = {v.x, v.y, v.z, v.w};
#pragma unroll
    for (int k = 0; k < 4; k++) {
      float lo = b2f((u16)(a[k] & 0xffff)) - l;
      float hi = b2f((u16)(a[k] >> 16)) - l;
      a[k] = ((u32)f2b(hi) << 16) | (u32)f2b(lo);
    }
    uint4 r; r.x = a[0]; r.y = a[1]; r.z = a[2]; r.w = a[3];
    ((uint4*)out)[g] = r;
  } else {
    float* out = (float*)outv;                 // 16,384,000 float4; 8000/row
    int row = g / 8000;
    float l = lse[row];
    float4 v = ((const float4*)out)[g];
    v.x -= l; v.y -= l; v.z -= l; v.w -= l;
    ((float4*)out)[g] = v;
  }
}

extern "C" void kernel_launch(void* const* d_in, const int* in_sizes, int n_in,
                              void* d_out, int out_size, void* d_ws, size_t ws_size,
                              hipStream_t stream) {
  const int* x = (const int*)d_in[0];

  char* ws = (char*)d_ws;
  float* gx2     = (float*)(ws);              // 25,165,824 B  [s][64][48][8] fp32
  u16*   feat    = (u16*)(ws + 25165824);     //  6,291,456 B  [2048][1536] bf16
  u16*   emb     = (u16*)(ws + 31457280);     //  2,097,152 B  [2048][512]  bf16
  u16*   logits  = (u16*)(ws + 33554432);     //  2,097,152 B  [2048][512]  bf16
  u32*   h_tag   = (u32*)(ws + 35651584);     //     65,536 B  [2][8][1024] tagged u32
  float* partial = (float*)(ws + 35717120);   //  4,096,000 B  [2048][500] fp32
  float* lse     = (float*)(ws + 39813120);   //      8,192 B  [2048] fp32
  u32*   flags   = (u32*)(ws + 39813120);     //        512 B  [2][64] advisory — aliases lse:
                                              //   k_gru (flags) completes before k_lse writes
  int*   dflag   = (int*)(ws + 39821312);     //        256 B
  u16*   embW_c  = (u16*)(ws + 39821568);     // 32,768,000 B
  u16*   Wih_c   = (u16*)(ws + 72589568);     //  3,145,728 B
  u16*   Whh_c   = (u16*)(ws + 75735296);     //  6,291,456 B
  u16*   linW_c  = (u16*)(ws + 82026752);     //  1,572,864 B
  u16*   bih_c   = (u16*)(ws + 83599616);     //      6,144 B
  u16*   bhh_c   = (u16*)(ws + 83605760);     //      6,144 B
  u16*   linb_c  = (u16*)(ws + 83611904);     //      1,024 B
  const size_t TOTAL_WS = 83612928;

  const u16 *embW, *W_ih, *W_hh, *b_ih, *b_hh, *lin_W, *lin_b;
  if (ws_size >= TOTAL_WS) {
    k_detect<<<1, 256, 0, stream>>>((const u32*)d_in[1], dflag);
    k_init<<<1, 256, 0, stream>>>(h_tag, flags, dflag, -1);
    k_conv<<<8000, 256, 0, stream>>>(d_in[1], embW_c, VV * EE, dflag);
    k_conv<<<1536, 256, 0, stream>>>(d_in[3], Whh_c, 3 * HH * HH, dflag);
    k_conv<<<768,  256, 0, stream>>>(d_in[2], Wih_c, 3 * HH * EE, dflag);
    k_conv<<<384,  256, 0, stream>>>(d_in[6], linW_c, EE * (HH + EE), dflag);
    k_conv<<<2,    256, 0, stream>>>(d_in[4], bih_c, 3 * HH, dflag);
    k_conv<<<2,    256, 0, stream>>>(d_in[5], bhh_c, 3 * HH, dflag);
    k_conv<<<1,    256, 0, stream>>>(d_in[7], linb_c, EE, dflag);
    embW = embW_c; W_ih = Wih_c; W_hh = Whh_c; b_ih = bih_c;
    b_hh = bhh_c; lin_W = linW_c; lin_b = linb_c;
  } else {
    k_init<<<1, 256, 0, stream>>>(h_tag, flags, dflag, 1);
    embW = (const u16*)d_in[1]; W_ih = (const u16*)d_in[2]; W_hh = (const u16*)d_in[3];
    b_ih = (const u16*)d_in[4]; b_hh = (const u16*)d_in[5];
    lin_W = (const u16*)d_in[6]; lin_b = (const u16*)d_in[7];
  }

  k_gather<<<2048, 64, 0, stream>>>(x, embW, emb, feat);
  k_gx<<<dim3(16, 24), 256, 0, stream>>>(emb, W_ih, b_ih, gx2);
  k_gru<<<GRU_BLOCKS, GRU_THREADS, 0, stream>>>(W_hh, b_hh, x, gx2, h_tag, flags, feat);
  k_lin<<<dim3(16, 4), 256, 0, stream>>>(feat, lin_W, lin_b, logits);
  k_scores<<<dim3(16, 250), 256, 0, stream>>>(logits, embW, d_out, partial, dflag);
  k_lse<<<2048, 64, 0, stream>>>(partial, lse);
  k_fix<<<64000, 256, 0, stream>>>(d_out, lse, dflag);
}

// Round 5
// 1535.359 us; speedup vs baseline: 1.3314x; 1.1771x over previous
//
#include <hip/hip_runtime.h>

typedef unsigned int u32;
typedef unsigned short u16;
typedef unsigned long long u64;
typedef __attribute__((ext_vector_type(8))) short short8;   // 8 bf16 = 4 VGPRs (MFMA A/B frag)
typedef __attribute__((ext_vector_type(4))) float floatx4;  // MFMA C/D frag

#define BB 8
#define SS 256
#define VV 32000
#define EE 512
#define HH 1024
#define GRU_BLOCKS 64
#define CONS_BLOCKS 192
#define NCHUNK 500       // 32000 / 64

__device__ __forceinline__ float b2f(u16 h) {
  union { u32 u; float f; } c; c.u = ((u32)h) << 16; return c.f;
}
__device__ __forceinline__ u16 f2b_bits(u32 u) {
  return (u16)((u + 0x7FFFu + ((u >> 16) & 1u)) >> 16);  // RNE
}
__device__ __forceinline__ u16 f2b(float f) {
  union { float f; u32 u; } c; c.f = f; return f2b_bits(c.u);
}

// ---------------- dtype detector: 1 = inputs are bf16, 0 = fp32 ----------------
__global__ __launch_bounds__(256) void k_detect(const u32* __restrict__ w, int* __restrict__ dflag) {
  __shared__ int cnt;
  if (threadIdx.x == 0) cnt = 0;
  __syncthreads();
  int c = 0;
  for (int i = threadIdx.x; i < 8192; i += 256) {
    u32 e8 = (w[i] >> 7) & 0xFF;
    c += (e8 >= 100 && e8 <= 144);
  }
  atomicAdd(&cnt, c);
  __syncthreads();
  if (threadIdx.x == 0) dflag[0] = (cnt * 2 > 8192) ? 1 : 0;
}

// ---------------- edge normalization: any float input -> bf16 ws copy ----------------
__global__ __launch_bounds__(256) void k_conv(const void* __restrict__ src, u16* __restrict__ dst,
                                              int n, const int* __restrict__ dflag) {
  int i = (blockIdx.x * 256 + threadIdx.x) * 8;
  if (i >= n) return;
  if (dflag[0]) {
    *(uint4*)(dst + i) = *(const uint4*)((const u16*)src + i);
  } else {
    const float* s = (const float*)src + i;
    uint4 a = *(const uint4*)s, b = *(const uint4*)(s + 4);
    u32 w0 = ((u32)f2b_bits(a.y) << 16) | f2b_bits(a.x);
    u32 w1 = ((u32)f2b_bits(a.w) << 16) | f2b_bits(a.z);
    u32 w2 = ((u32)f2b_bits(b.y) << 16) | f2b_bits(b.x);
    u32 w3 = ((u32)f2b_bits(b.w) << 16) | f2b_bits(b.z);
    uint4 r; r.x = w0; r.y = w1; r.z = w2; r.w = w3;
    *(uint4*)(dst + i) = r;
  }
}

// ---------------- init: zero h-exchange + flags + chunk counters (+ dflag force) ----------
__global__ __launch_bounds__(256) void k_init(u32* h_tag, u32* flags, u32* sync,
                                              int* dflag, int setflag) {
  int t = threadIdx.x;
  for (int i = t; i < 2 * 8192; i += 256) h_tag[i] = 0;
  if (t < 128) flags[t] = 0;
  if (t < 16) sync[t] = 0;
  if (t == 0 && setflag >= 0) dflag[0] = setflag;
}

// ---------------- embedding gather (feat rows in [s*8+b] order) ----------------
__global__ __launch_bounds__(64) void k_gather(const int* __restrict__ x,
                                               const u16* __restrict__ embW,
                                               u16* __restrict__ emb,
                                               u16* __restrict__ feat) {
  int row = blockIdx.x, l = threadIdx.x;     // row = b*256+s
  int tok = x[row];
  uint4 v = ((const uint4*)(embW + (size_t)tok * EE))[l];
  ((uint4*)(emb + (size_t)row * EE))[l] = v;
  int rf = ((row & 255) << 3) | (row >> 8);  // [s*8+b] row for feat
  ((uint4*)(feat + (size_t)rf * 1536 + HH))[l] = v;   // feat = [ctx | emb]
}

// ---------------- shared GEMM core: C[128x128] = A[128xK] * B[128xK]^T ----------------
template <int KTOT>
__device__ __forceinline__ void gemm_core(const u16* __restrict__ A, int lda,
                                          const u16* __restrict__ Bm, int ldb,
                                          int m0, int n0, floatx4 acc[4][4]) {
  __shared__ __align__(16) u16 As[128 * 64];
  __shared__ __align__(16) u16 Bs[128 * 64];
  const int tid = threadIdx.x;
  const int lane = tid & 63, w = tid >> 6;
  const int wm = w & 1, wn = w >> 1;
  const int col16 = lane & 15, quad = lane >> 4;
  floatx4 z = {0.f, 0.f, 0.f, 0.f};
  for (int i = 0; i < 4; i++)
    for (int j = 0; j < 4; j++) acc[i][j] = z;

  for (int k0 = 0; k0 < KTOT; k0 += 64) {
#pragma unroll
    for (int i = 0; i < 4; i++) {
      int c = tid + i * 256;
      int r = c >> 3, off = (c & 7) * 8;
      *(uint4*)&As[r * 64 + off] = *(const uint4*)&A[(size_t)(m0 + r) * lda + k0 + off];
      *(uint4*)&Bs[r * 64 + off] = *(const uint4*)&Bm[(size_t)(n0 + r) * ldb + k0 + off];
    }
    __syncthreads();
#pragma unroll
    for (int kk = 0; kk < 2; kk++) {
      short8 af[4], bf[4];
#pragma unroll
      for (int i = 0; i < 4; i++) {
        af[i] = *(const short8*)&As[(wm * 64 + i * 16 + col16) * 64 + kk * 32 + quad * 8];
        bf[i] = *(const short8*)&Bs[(wn * 64 + i * 16 + col16) * 64 + kk * 32 + quad * 8];
      }
#pragma unroll
      for (int i = 0; i < 4; i++)
#pragma unroll
        for (int j = 0; j < 4; j++)
          acc[i][j] = __builtin_amdgcn_mfma_f32_16x16x32_bf16(af[i], bf[j], acc[i][j], 0, 0, 0);
    }
    __syncthreads();
  }
}

// ---------------- gx = emb @ W_ih^T + b_ih, scattered to [s][gb][48][8] fp32 ----------------
__global__ __launch_bounds__(256) void k_gx(const u16* __restrict__ emb,
                                            const u16* __restrict__ W_ih,
                                            const u16* __restrict__ b_ih,
                                            float* __restrict__ gx2) {
  floatx4 acc[4][4];
  int bm = blockIdx.x, bn = blockIdx.y;
  gemm_core<EE>(emb, EE, W_ih, EE, bm * 128, bn * 128, acc);
  const int tid = threadIdx.x, lane = tid & 63, w = tid >> 6;
  const int wm = w & 1, wn = w >> 1, col16 = lane & 15, quad = lane >> 4;
#pragma unroll
  for (int j = 0; j < 4; j++) {
    int g = bn * 128 + wn * 64 + j * 16 + col16;
    float bias = b2f(b_ih[g]);
    int grp = g >> 10, colh = g & 1023;
    int gb = colh >> 4, slot = grp * 16 + (colh & 15);
#pragma unroll
    for (int i = 0; i < 4; i++)
#pragma unroll
      for (int e = 0; e < 4; e++) {
        int row = bm * 128 + wm * 64 + i * 16 + quad * 4 + e;
        int b = row >> 8, s = row & 255;
        gx2[((size_t)(s * 64 + gb) * 48 + slot) * 8 + b] = acc[i][j][e] + bias;
      }
  }
}

// ---------------- mega-kernel: persistent GRU (blocks 0-63) + lin/scores consumers -------
// GRU role: R4's advisory-flag + authoritative-tag exchange, 256 threads (16 poll words/t).
// Publishes feat ctx-cols as packed u32 AGENT atomics (cross-XCD visible); every 32 steps:
// __syncthreads (per-wave vmcnt drain = release) + chunk_done[c]++ (agent atomicAdd).
// Consumer role (blocks 64-255): 8 chunks x (8 lin tiles + 500 scores tiles), strided over
// 192 blocks. lin gated on chunk_done[c]==64; writes logits via packed u32 agent atomics,
// then barrier-drain + lin_done[c]++. scores gated on lin_done[c]==8; C-write remaps rows
// [s*8+b] -> [b*256+s]. All intra-kernel producer->consumer surfaces are agent atomics
// (per-XCD L2s are non-coherent); readers first-touch data only after their gate.
__global__ __launch_bounds__(256, 1) void k_mega(const u16* __restrict__ W_hh,
                                                 const u16* __restrict__ b_hh,
                                                 const int* __restrict__ x,
                                                 const float* __restrict__ gx2,
                                                 u32* __restrict__ h_tag,
                                                 u32* __restrict__ flags,
                                                 u16* __restrict__ feat,
                                                 const u16* __restrict__ lin_W,
                                                 const u16* __restrict__ lin_b,
                                                 u16* __restrict__ logits,
                                                 const u16* __restrict__ embW,
                                                 void* __restrict__ outv,
                                                 float* __restrict__ partial,
                                                 const int* __restrict__ dflag,
                                                 u32* __restrict__ sync) {
  u32* chunk_done = sync;       // [8] GRU blocks done with chunk c
  u32* lin_done   = sync + 8;   // [8] lin tiles done for chunk c

  if (blockIdx.x < GRU_BLOCKS) {
    // ================= GRU role =================
    __shared__ __align__(16) u16 h_lds[16][1032];  // rows 8..15 stay zero (MFMA M-pad)
    __shared__ float gh[3][16][8];
    __shared__ float hold[16][8];
    __shared__ float bhh[48];
    __shared__ int x_s[2048];

    const int tid = threadIdx.x;
    const int lane = tid & 63, w = tid >> 6;       // waves 0-2: gates r,z,n; wave 3: staging
    const int blk = blockIdx.x, hc = blk * 16;
    const int col16 = lane & 15, quad = lane >> 4;

    for (int i = tid; i < 16 * 1032; i += 256) ((u16*)h_lds)[i] = 0;
    for (int i = tid; i < 2048; i += 256) x_s[i] = x[i];
    if (tid < 128) hold[tid & 15][tid >> 4] = 0.f;
    if (tid < 48) bhh[tid] = b2f(b_hh[(tid >> 4) * HH + hc + (tid & 15)]);

    short8 Wf[32];
    if (w < 3) {
      int grow = w * HH + hc + col16;
      const u16* wp = W_hh + (size_t)grow * HH + quad * 8;
#pragma unroll
      for (int t = 0; t < 32; t++) Wf[t] = *(const short8*)(wp + t * 32);
    }
    __syncthreads();

    const int cj = tid & 15, cb = tid >> 4;
#pragma unroll 1
    for (int s = 0; s < SS; s++) {
      // prefetch this step's input gates (independent of h; hides under flag wait)
      float xr = 0.f, xz = 0.f, xn = 0.f;
      if (tid < 128) {
        const float* gp = gx2 + (size_t)(s * 64 + blk) * 384;
        xr = gp[cj * 8 + cb];
        xz = gp[128 + cj * 8 + cb];
        xn = gp[256 + cj * 8 + cb];
      }
      // advisory flag gate: thread t<64 spins on block t's flag (own block skipped)
      if (tid < 64 && tid != blk) {
        const u32* fp = flags + (s & 1) * 64 + tid;
        int guard = 0;
        while (__hip_atomic_load(fp, __ATOMIC_RELAXED, __HIP_MEMORY_SCOPE_AGENT) != (u32)s) {
          if (++guard > (1 << 20)) break;  // livelock safety
        }
      }
      __syncthreads();
      // bulk tagged load + verify (typically one round). Own 16 cols skipped (LDS bypass).
      {
        const u64* hb = (const u64*)(h_tag + (size_t)(s & 1) * 8192);
        const u32 want = (u32)(s & 0xFFFF);
        u64 vals[16];
        u32 pend = 0;
#pragma unroll
        for (int i = 0; i < 16; i++) {
          int pr = tid + i * 256;
          if (((pr & 511) >> 3) != blk) pend |= 1u << i;
        }
        int guard = 0;
        while (pend) {
#pragma unroll
          for (int i = 0; i < 16; i++)
            if (pend & (1u << i))
              vals[i] = __hip_atomic_load(hb + (tid + i * 256),
                                          __ATOMIC_RELAXED, __HIP_MEMORY_SCOPE_AGENT);
#pragma unroll
          for (int i = 0; i < 16; i++)
            if (pend & (1u << i)) {
              u64 v = vals[i];
              if ((u32)(v & 0xFFFFu) == want && ((u32)(v >> 32) & 0xFFFFu) == want) {
                int pr = tid + i * 256;
                u32 packed = ((u32)(v >> 16) & 0xFFFFu) | ((u32)(v >> 48) << 16);
                *(u32*)&h_lds[pr >> 9][(pr & 511) * 2] = packed;
                pend &= ~(1u << i);
              }
            }
          if (pend) {
            if (++guard > (1 << 14)) break;  // livelock safety (wrong results, no hang)
          }
        }
      }
      __syncthreads();
      // g_h = h @ W_hh^T for this wave's 16 gate rows (K=1024: 32 MFMAs, 2 chains)
      if (w < 3) {
        const u16* hp = &h_lds[col16][quad * 8];
        floatx4 a0 = {0.f, 0.f, 0.f, 0.f}, a1 = {0.f, 0.f, 0.f, 0.f};
#pragma unroll
        for (int t = 0; t < 32; t += 2) {
          short8 f0 = *(const short8*)(hp + t * 32);
          short8 f1 = *(const short8*)(hp + t * 32 + 32);
          a0 = __builtin_amdgcn_mfma_f32_16x16x32_bf16(f0, Wf[t], a0, 0, 0, 0);
          a1 = __builtin_amdgcn_mfma_f32_16x16x32_bf16(f1, Wf[t + 1], a1, 0, 0, 0);
        }
        a0 += a1;
        if (quad < 2) {
#pragma unroll
          for (int e = 0; e < 4; e++) gh[w][col16][quad * 4 + e] = a0[e];
        }
      }
      __syncthreads();
      // gate combine + state update + tagged publish for owned 16 h-cols x 8 batches
      if (tid < 128) {
        float hr = gh[0][cj][cb] + bhh[cj];
        float hz = gh[1][cj][cb] + bhh[16 + cj];
        float hn = gh[2][cj][cb] + bhh[32 + cj];
        float r = 1.f / (1.f + __expf(-(xr + hr)));
        float z = 1.f / (1.f + __expf(-(xz + hz)));
        float tn = xn + r * hn;
        float n = 1.f - 2.f / (1.f + __expf(2.f * tn));  // tanh via exp
        float ho = hold[cj][cb];
        float hnew = (1.f - z) * n + z * ho;
        int pad = (x_s[cb * SS + s] == 0);
        if (pad) hnew = ho;
        hold[cj][cb] = hnew;
        u16 hb16 = f2b(hnew);
        u32 tw = ((u32)hb16 << 16) | (u32)((s + 1) & 0xFFFF);
        __hip_atomic_store(h_tag + (size_t)((s + 1) & 1) * 8192 + cb * 1024 + hc + cj, tw,
                           __ATOMIC_RELAXED, __HIP_MEMORY_SCOPE_AGENT);
        h_lds[cb][hc + cj] = hb16;  // own cols bypass global round-trip
        // feat ctx publish: packed u32 agent atomics (cross-XCD visible to consumers)
        u32 fv = pad ? 0u : (u32)hb16;
        u32 ov = (u32)__shfl_xor((int)fv, 1, 64);
        if (!(cj & 1))
          __hip_atomic_store((u32*)(feat + (size_t)(s * 8 + cb) * 1536 + hc + cj),
                             fv | (ov << 16), __ATOMIC_RELAXED, __HIP_MEMORY_SCOPE_AGENT);
      }
      // advisory flag: fire-and-forget, no drain (tags remain the authority)
      if (tid == 0)
        __hip_atomic_store(flags + ((s + 1) & 1) * 64 + blk, (u32)(s + 1),
                           __ATOMIC_RELAXED, __HIP_MEMORY_SCOPE_AGENT);
      // chunk release: barrier drains each wave's stores (vmcnt(0) before s_barrier),
      // then one counter bump. Once per 32 steps -> negligible on the exchange path.
      if ((s & 31) == 31) {
        __syncthreads();
        if (tid == 0)
          __hip_atomic_fetch_add(chunk_done + (s >> 5), 1u,
                                 __ATOMIC_RELAXED, __HIP_MEMORY_SCOPE_AGENT);
      }
    }
  } else {
    // ================= consumer role: lin + scores tiles, chunk-gated =================
    const int cid = blockIdx.x - GRU_BLOCKS;
    const int tid = threadIdx.x, lane = tid & 63, w4 = tid >> 6;
    const int wm = w4 & 1, wn = w4 >> 1, col16 = lane & 15, quad = lane >> 4;
    const int bf = dflag[0];
    u16* out16 = (u16*)outv;
    float* out32 = (float*)outv;

    for (int t = cid; t < 8 * 508; t += CONS_BLOCKS) {
      int c = t / 508, i = t - c * 508;
      floatx4 acc[4][4];
      if (i < 8) {
        // ---- lin tile: logits = tanh(feat @ lin_W^T + lin_b), rows chunk c ----
        if (tid == 0) {
          while (__hip_atomic_load(chunk_done + c, __ATOMIC_RELAXED,
                                   __HIP_MEMORY_SCOPE_AGENT) < (u32)GRU_BLOCKS)
            __builtin_amdgcn_s_sleep(8);
        }
        __syncthreads();
        int mt = i & 1, bn = i >> 1;
        gemm_core<1536>(feat, 1536, lin_W, 1536, c * 256 + mt * 128, bn * 128, acc);
#pragma unroll
        for (int j = 0; j < 4; j++) {
          int col = bn * 128 + wn * 64 + j * 16 + col16;
          float bias = b2f(lin_b[col]);
#pragma unroll
          for (int ii = 0; ii < 4; ii++)
#pragma unroll
            for (int e = 0; e < 4; e++) {
              int row = c * 256 + mt * 128 + wm * 64 + ii * 16 + quad * 4 + e;
              u32 mine = (u32)f2b(tanhf(acc[ii][j][e] + bias));
              u32 oth = (u32)__shfl_xor((int)mine, 1, 64);
              if (!(col16 & 1))
                __hip_atomic_store((u32*)(logits + (size_t)row * EE + col),
                                   mine | (oth << 16),
                                   __ATOMIC_RELAXED, __HIP_MEMORY_SCOPE_AGENT);
            }
        }
        __syncthreads();  // drains each wave's logits stores (release)
        if (tid == 0)
          __hip_atomic_fetch_add(lin_done + c, 1u,
                                 __ATOMIC_RELAXED, __HIP_MEMORY_SCOPE_AGENT);
      } else {
        // ---- scores tile: out = logits @ embW^T (+ per-chunk sumexp) ----
        int j2 = i - 8;
        int mt = j2 & 1, bn = j2 >> 1;
        if (tid == 0) {
          while (__hip_atomic_load(lin_done + c, __ATOMIC_RELAXED,
                                   __HIP_MEMORY_SCOPE_AGENT) < 8u)
            __builtin_amdgcn_s_sleep(8);
        }
        __syncthreads();
        gemm_core<EE>(logits, EE, embW, EE, c * 256 + mt * 128, bn * 128, acc);
#pragma unroll
        for (int ii = 0; ii < 4; ii++) {
#pragma unroll
          for (int e = 0; e < 4; e++) {
            int rf = c * 256 + mt * 128 + wm * 64 + ii * 16 + quad * 4 + e;
            int ro = ((rf & 7) << 8) | (rf >> 3);   // [s*8+b] -> [b*256+s]
            size_t ob = (size_t)ro * VV + bn * 128 + wn * 64;
            float sl = 0.f;
#pragma unroll
            for (int jj = 0; jj < 4; jj++) {
              float v = acc[ii][jj][e];
              if (bf) out16[ob + jj * 16 + col16] = f2b(v);
              else    out32[ob + jj * 16 + col16] = v;
              sl += __expf(v);  // |score| <= ~30: fp32-safe without max
            }
            sl += __shfl_xor(sl, 1, 64);
            sl += __shfl_xor(sl, 2, 64);
            sl += __shfl_xor(sl, 4, 64);
            sl += __shfl_xor(sl, 8, 64);
            if (col16 == 0) partial[(size_t)ro * NCHUNK + bn * 2 + wn] = sl;
          }
        }
      }
    }
  }
}

// ---------------- lse[row] = log(sum of 500 chunk sums) ----------------
__global__ __launch_bounds__(64) void k_lse(const float* __restrict__ partial,
                                            float* __restrict__ lse) {
  int row = blockIdx.x, lane = threadIdx.x;
  float s = 0.f;
  for (int c = lane; c < NCHUNK; c += 64) s += partial[(size_t)row * NCHUNK + c];
#pragma unroll
  for (int d = 32; d >= 1; d >>= 1) s += __shfl_xor(s, d, 64);
  if (lane == 0) lse[row] = logf(s);
}

// ---------------- out -= lse[row] (in place, 16 B per thread, dual dtype) ----------------
__global__ __launch_bounds__(256) void k_fix(void* __restrict__ outv,
                                             const float* __restrict__ lse,
                                             const int* __restrict__ dflag) {
  int g = blockIdx.x * 256 + threadIdx.x;      // grid: 64000*256 = 16,384,000 granules
  if (dflag[0]) {
    if (g >= 8192000) return;                  // 8,192,000 uint4 of bf16 out; 4000/row
    u16* out = (u16*)outv;
    int row = g / 4000;
    float l = lse[row];
    uint4 v = ((const uint4*)out)[g];
    u32 a[4] = {v.x, v.y, v.z, v.w};
#pragma unroll
    for (int k = 0; k < 4; k++) {
      float lo = b2f((u16)(a[k] & 0xffff)) - l;
      float hi = b2f((u16)(a[k] >> 16)) - l;
      a[k] = ((u32)f2b(hi) << 16) | (u32)f2b(lo);
    }
    uint4 r; r.x = a[0]; r.y = a[1]; r.z = a[2]; r.w = a[3];
    ((uint4*)out)[g] = r;
  } else {
    float* out = (float*)outv;                 // 16,384,000 float4; 8000/row
    int row = g / 8000;
    float l = lse[row];
    float4 v = ((const float4*)out)[g];
    v.x -= l; v.y -= l; v.z -= l; v.w -= l;
    ((float4*)out)[g] = v;
  }
}

extern "C" void kernel_launch(void* const* d_in, const int* in_sizes, int n_in,
                              void* d_out, int out_size, void* d_ws, size_t ws_size,
                              hipStream_t stream) {
  const int* x = (const int*)d_in[0];

  char* ws = (char*)d_ws;
  float* gx2     = (float*)(ws);              // 25,165,824 B  [s][64][48][8] fp32
  u16*   feat    = (u16*)(ws + 25165824);     //  6,291,456 B  [2048][1536] bf16, [s*8+b] rows
  u16*   emb     = (u16*)(ws + 31457280);     //  2,097,152 B  [2048][512]  bf16, [b*256+s]
  u16*   logits  = (u16*)(ws + 33554432);     //  2,097,152 B  [2048][512]  bf16, [s*8+b] rows
  u32*   h_tag   = (u32*)(ws + 35651584);     //     65,536 B  [2][8][1024] tagged u32
  float* partial = (float*)(ws + 35717120);   //  4,096,000 B  [2048][500] fp32
  float* lse     = (float*)(ws + 39813120);   //      8,192 B  [2048] fp32
  u32*   flags   = (u32*)(ws + 39813120);     //        512 B  [2][64] advisory — aliases lse:
                                              //   k_mega (flags) completes before k_lse writes
  int*   dflag   = (int*)(ws + 39821312);     //       dflag[0] + sync counters below
  u32*   sync    = (u32*)(ws + 39821312 + 128); //     64 B  chunk_done[8] + lin_done[8]
  u16*   embW_c  = (u16*)(ws + 39821568);     // 32,768,000 B
  u16*   Wih_c   = (u16*)(ws + 72589568);     //  3,145,728 B
  u16*   Whh_c   = (u16*)(ws + 75735296);     //  6,291,456 B
  u16*   linW_c  = (u16*)(ws + 82026752);     //  1,572,864 B
  u16*   bih_c   = (u16*)(ws + 83599616);     //      6,144 B
  u16*   bhh_c   = (u16*)(ws + 83605760);     //      6,144 B
  u16*   linb_c  = (u16*)(ws + 83611904);     //      1,024 B
  const size_t TOTAL_WS = 83612928;

  const u16 *embW, *W_ih, *W_hh, *b_ih, *b_hh, *lin_W, *lin_b;
  if (ws_size >= TOTAL_WS) {
    k_detect<<<1, 256, 0, stream>>>((const u32*)d_in[1], dflag);
    k_init<<<1, 256, 0, stream>>>(h_tag, flags, sync, dflag, -1);
    k_conv<<<8000, 256, 0, stream>>>(d_in[1], embW_c, VV * EE, dflag);
    k_conv<<<1536, 256, 0, stream>>>(d_in[3], Whh_c, 3 * HH * HH, dflag);
    k_conv<<<768,  256, 0, stream>>>(d_in[2], Wih_c, 3 * HH * EE, dflag);
    k_conv<<<384,  256, 0, stream>>>(d_in[6], linW_c, EE * (HH + EE), dflag);
    k_conv<<<2,    256, 0, stream>>>(d_in[4], bih_c, 3 * HH, dflag);
    k_conv<<<2,    256, 0, stream>>>(d_in[5], bhh_c, 3 * HH, dflag);
    k_conv<<<1,    256, 0, stream>>>(d_in[7], linb_c, EE, dflag);
    embW = embW_c; W_ih = Wih_c; W_hh = Whh_c; b_ih = bih_c;
    b_hh = bhh_c; lin_W = linW_c; lin_b = linb_c;
  } else {
    k_init<<<1, 256, 0, stream>>>(h_tag, flags, sync, dflag, 1);
    embW = (const u16*)d_in[1]; W_ih = (const u16*)d_in[2]; W_hh = (const u16*)d_in[3];
    b_ih = (const u16*)d_in[4]; b_hh = (const u16*)d_in[5];
    lin_W = (const u16*)d_in[6]; lin_b = (const u16*)d_in[7];
  }

  k_gather<<<2048, 64, 0, stream>>>(x, embW, emb, feat);
  k_gx<<<dim3(16, 24), 256, 0, stream>>>(emb, W_ih, b_ih, gx2);
  k_mega<<<GRU_BLOCKS + CONS_BLOCKS, 256, 0, stream>>>(W_hh, b_hh, x, gx2, h_tag, flags,
                                                       feat, lin_W, lin_b, logits, embW,
                                                       d_out, partial, dflag, sync);
  k_lse<<<2048, 64, 0, stream>>>(partial, lse);
  k_fix<<<64000, 256, 0, stream>>>(d_out, lse, dflag);
}